// Round 5
// baseline (105.924 us; speedup 1.0000x reference)
//
#include <hip/hip_runtime.h>

#define B 32
#define L 512
#define D 768
#define M 24
#define P (M * (M - 1))   // 552
#define Q4 (D / 4)        // 192 float4 per half-row

typedef float f32x4 __attribute__((ext_vector_type(4)));

// One block per (b, m): 384 threads.
// Gather: threads 0..191 accumulate EVEN span rows, 192..383 ODD span rows
// (fully unrolled, uniform guards -> all loads issue in parallel), partials
// combined via LDS. Write: threads 0..191 write the OBJ half of 23 rows,
// threads 192..383 the SUB half of 23 rows. Threads 0..22 emit pair rows.
__global__ void fused_kernel(const float* __restrict__ seq,   // B,L,D
                             const int*   __restrict__ head,  // B,L
                             const int*   __restrict__ em,    // B,M,2
                             float*       __restrict__ out)   // B*P*1536 rel | B*P*5 pairs
{
    __shared__ f32x4 poolA[Q4];   // even-row partial
    __shared__ f32x4 poolB[Q4];   // odd-row partial

    int bm = blockIdx.x;           // 0 .. B*M-1
    int b = bm / M, m = bm - b * M;
    int t  = threadIdx.x;          // 0..383
    int hf = t >= Q4;              // 0: even rows + obj half, 1: odd rows + sub half
    int tq = hf ? t - Q4 : t;      // 0..191

    int s = em[bm * 2 + 0];
    int e = em[bm * 2 + 1];
    int len = e - s;               // 1..15 (block-uniform)

    const float* seqb  = seq  + (size_t)b * L * D;
    const int*   headb = head + b * L;

    // ---- parallel gather ----
    int cnt = (len - hf + 1) >> 1;        // rows this half handles (<=8)
    f32x4 vv[8];
    #pragma unroll
    for (int r = 0; r < 8; ++r) {
        if (r < cnt) {                    // block-half-uniform branch
            int l = s + hf + 2 * r;
            vv[r] = ((const f32x4*)(seqb + (size_t)headb[l] * D))[tq];
        }
    }
    f32x4 acc = (f32x4)(0.f);
    #pragma unroll
    for (int r = 0; r < 8; ++r)
        if (r < cnt) acc += vv[r];
    (hf ? poolB : poolA)[tq] = acc;
    __syncthreads();

    float inv = 1.0f / (float)len;
    f32x4 v = (poolA[tq] + poolB[tq]) * inv;

    // ---- fan-out writes ----
    f32x4* outq = (f32x4*)out;             // rel rows: 384 float4 each
    size_t rowbase = (size_t)b * P;

    if (!hf) {
        // OBJ half: rows m*23 + r, quad offset tq
        size_t q = (rowbase + (size_t)m * 23) * 384 + tq;
        #pragma unroll
        for (int r = 0; r < 23; ++r) {
            __builtin_nontemporal_store(v, &outq[q]);
            q += 384;
        }
        if (tq < 23) {
            int r = tq;
            int j = (r < m) ? r : r + 1;
            float* o = out + (size_t)B * P * 2 * D
                     + (size_t)(rowbase + (size_t)m * 23 + r) * 5;
            o[0] = (float)b;
            o[1] = (float)s;
            o[2] = (float)e;
            o[3] = (float)em[(b * M + j) * 2 + 0];
            o[4] = (float)em[(b * M + j) * 2 + 1];
        }
    } else {
        // SUB half: this mention is j == m; for each i != m, r = (m<i) ? m : m-1
        #pragma unroll
        for (int i = 0; i < M; ++i) {
            if (i == m) continue;
            int r = (m < i) ? m : m - 1;
            size_t row = rowbase + (size_t)i * 23 + r;
            __builtin_nontemporal_store(v, &outq[row * 384 + Q4 + tq]);
        }
    }
}

extern "C" void kernel_launch(void* const* d_in, const int* in_sizes, int n_in,
                              void* d_out, int out_size, void* d_ws, size_t ws_size,
                              hipStream_t stream) {
    const float* seq  = (const float*)d_in[0];
    const int*   head = (const int*)d_in[1];
    const int*   em   = (const int*)d_in[2];
    float* out = (float*)d_out;

    fused_kernel<<<B * M, 2 * Q4, 0, stream>>>(seq, head, em, out);
}

// Round 6
// 26.721 us; speedup vs baseline: 3.9640x; 3.9640x over previous
//
#include <hip/hip_runtime.h>

#define B 32
#define L 512
#define D 768
#define M 24
#define P (M * (M - 1))   // 552
#define Q4 (D / 4)        // 192 float4 per half-row

typedef float f32x4 __attribute__((ext_vector_type(4)));

// One block per (b, m): 384 threads.
// Gather: threads 0..191 accumulate EVEN span rows, 192..383 ODD rows.
// All head-index and row loads are UNCONDITIONAL (clamped addresses) so the
// unrolled arrays stay in registers (R5 used guarded writes -> scratch -> 4x).
// Out-of-range rows are masked out of the ADD with a value-select.
// Write: threads 0..191 write the OBJ half of 23 rows, 192..383 the SUB half.
__global__ void fused_kernel(const float* __restrict__ seq,   // B,L,D
                             const int*   __restrict__ head,  // B,L
                             const int*   __restrict__ em,    // B,M,2
                             float*       __restrict__ out)   // B*P*1536 rel | B*P*5 pairs
{
    __shared__ f32x4 pool[2][Q4];  // 6 KB

    int bm = blockIdx.x;           // 0 .. B*M-1
    int b = bm / M, m = bm - b * M;
    int t  = threadIdx.x;          // 0..383
    int hf = t >= Q4;              // 0: even rows + obj half, 1: odd rows + sub half
    int tq = hf ? t - Q4 : t;      // 0..191

    int s = em[bm * 2 + 0];
    int e = em[bm * 2 + 1];
    int len = e - s;               // 1..15 (block-uniform)

    const float* seqb  = seq  + (size_t)b * L * D;
    const int*   headb = head + b * L;

    // ---- parallel gather, scratch-free ----
    int cnt = (len - hf + 1) >> 1;        // rows this half accumulates (<=8)
    int hidx[8];
    #pragma unroll
    for (int r = 0; r < 8; ++r) {
        int l = s + hf + 2 * r;
        l = (l < e) ? l : s;              // clamp to a valid row
        hidx[r] = headb[l];               // unconditional: stays in registers
    }
    f32x4 vv[8];
    #pragma unroll
    for (int r = 0; r < 8; ++r)
        vv[r] = ((const f32x4*)(seqb + (size_t)hidx[r] * D))[tq];  // unconditional
    f32x4 acc = (f32x4)(0.f);
    #pragma unroll
    for (int r = 0; r < 8; ++r)
        acc += (r < cnt) ? vv[r] : (f32x4)(0.f);                   // VALU mask
    pool[hf][tq] = acc;
    __syncthreads();

    float inv = 1.0f / (float)len;
    f32x4 v = (pool[0][tq] + pool[1][tq]) * inv;

    // ---- fan-out writes (identical to R4) ----
    f32x4* outq = (f32x4*)out;             // rel rows: 384 float4 each
    size_t rowbase = (size_t)b * P;

    if (!hf) {
        // OBJ half: rows m*23 + r, quad offset tq
        size_t q = (rowbase + (size_t)m * 23) * 384 + tq;
        #pragma unroll
        for (int r = 0; r < 23; ++r) {
            __builtin_nontemporal_store(v, &outq[q]);
            q += 384;
        }
        if (tq < 23) {
            int r = tq;
            int j = (r < m) ? r : r + 1;
            float* o = out + (size_t)B * P * 2 * D
                     + (size_t)(rowbase + (size_t)m * 23 + r) * 5;
            o[0] = (float)b;
            o[1] = (float)s;
            o[2] = (float)e;
            o[3] = (float)em[(b * M + j) * 2 + 0];
            o[4] = (float)em[(b * M + j) * 2 + 1];
        }
    } else {
        // SUB half: this mention is j == m; for each i != m, r = (m<i) ? m : m-1
        #pragma unroll
        for (int i = 0; i < M; ++i) {
            if (i == m) continue;
            int r = (m < i) ? m : m - 1;
            size_t row = rowbase + (size_t)i * 23 + r;
            __builtin_nontemporal_store(v, &outq[row * 384 + Q4 + tq]);
        }
    }
}

extern "C" void kernel_launch(void* const* d_in, const int* in_sizes, int n_in,
                              void* d_out, int out_size, void* d_ws, size_t ws_size,
                              hipStream_t stream) {
    const float* seq  = (const float*)d_in[0];
    const int*   head = (const int*)d_in[1];
    const int*   em   = (const int*)d_in[2];
    float* out = (float*)d_out;

    fused_kernel<<<B * M, 2 * Q4, 0, stream>>>(seq, head, em, out);
}